// Round 5
// baseline (1670.069 us; speedup 1.0000x reference)
//
#include <hip/hip_runtime.h>
#include <hip/hip_fp16.h>

typedef _Float16 half_t;
typedef _Float16 half8 __attribute__((ext_vector_type(8)));
typedef float floatx4 __attribute__((ext_vector_type(4)));

// ---- sizes ----
#define T_STEPS 300
#define NMB     1024                 // N*M batch
#define BSS     6                    // steps per phase-A block (300 = 50*6)

// ws layout (bytes)
#define XT_OFF   0ULL
#define XT_BYTES ((unsigned long long)T_STEPS*NMB*64*2)
#define WCH_OFF  (XT_OFF + XT_BYTES)          // wcomb as f16 [512][64]
#define WCH_BYTES (512ULL*64*2)
#define BC_OFF   (WCH_OFF + WCH_BYTES)        // biasc f32 [512]

// L_hat = -D^-1/2 A D^-1/2 for the hardcoded 15-node skeleton (row=dst, col=src)
#define S2 0.70710678118654752f
#define QH 0.5f
#define UU 0.40824829046386302f
#define TH 0.33333333333333333f
__constant__ float LHAT[225] = {
  0,0,-S2,0,0,0,0,0,0,0,0,0,0,0,0,
  0,0,0,-S2,0,0,0,0,0,0,0,0,0,0,0,
  -S2,0,0,0,-QH,0,0,0,0,0,0,0,0,0,0,
  0,-S2,0,0,0,-QH,0,0,0,0,0,0,0,0,0,
  0,0,-QH,0,0,0,0,0,0,0,0,0,0,0,-UU,
  0,0,0,-QH,0,0,0,0,0,0,0,0,0,0,-UU,
  0,0,0,0,0,0,0,0,-S2,0,0,0,0,0,0,
  0,0,0,0,0,0,0,0,0,-S2,0,0,0,0,0,
  0,0,0,0,0,0,-S2,0,0,0,-QH,0,0,0,0,
  0,0,0,0,0,0,0,-S2,0,0,0,-QH,0,0,0,
  0,0,0,0,0,0,0,0,-QH,0,0,0,0,-UU,0,
  0,0,0,0,0,0,0,0,0,-QH,0,0,0,-UU,0,
  0,0,0,0,0,0,0,0,0,0,0,0,0,0,0,
  0,0,0,0,0,0,0,0,0,0,-UU,-UU,0,0,0,
  0,0,0,0,-UU,-UU,0,0,0,0,0,0,0,-TH,0
};

// Fast gate math: v_exp_f32 + v_rcp_f32 (approx, ~1 ulp).
__device__ __forceinline__ float frcp(float x)  { return __builtin_amdgcn_rcpf(x); }
__device__ __forceinline__ float fsig(float x)  { return frcp(1.f + __expf(-x)); }
__device__ __forceinline__ float ftanh(float x) { return 2.f*frcp(1.f + __expf(-2.f*x)) - 1.f; }

__device__ __forceinline__ half8 load_w8(const float* p) {
  const float4* q = (const float4*)p;
  float4 a = q[0], b = q[1];
  half8 f;
  f[0]=(half_t)a.x; f[1]=(half_t)a.y; f[2]=(half_t)a.z; f[3]=(half_t)a.w;
  f[4]=(half_t)b.x; f[5]=(half_t)b.y; f[6]=(half_t)b.z; f[7]=(half_t)b.w;
  return f;
}

// ---- K0: fold ChebConv into layer-0 input projection: wcomb_h f16[512][64], biasc[512]
__global__ void k_prep(const float* __restrict__ w0, const float* __restrict__ w1,
                       const float* __restrict__ cb, const float* __restrict__ wih0,
                       const float* __restrict__ bih0, const float* __restrict__ bhh0,
                       half_t* __restrict__ wcomb_h, float* __restrict__ biasc) {
  const int n = threadIdx.x; // 512 threads, 1 block
  float wrow[45];
  #pragma unroll
  for (int i=0;i<45;i++) wrow[i] = wih0[n*45+i];
  float P[45];
  #pragma unroll
  for (int i=0;i<15;i++)
    #pragma unroll
    for (int c=0;c<3;c++) {
      float s = 0.f;
      #pragma unroll
      for (int cp=0;cp<3;cp++) s += wrow[i*3+cp]*w1[cp*3+c];
      P[i*3+c] = s;
    }
  #pragma unroll
  for (int j=0;j<15;j++)
    #pragma unroll
    for (int c=0;c<3;c++) {
      float s = 0.f;
      #pragma unroll
      for (int cp=0;cp<3;cp++) s += wrow[j*3+cp]*w0[cp*3+c];
      #pragma unroll
      for (int i=0;i<15;i++) s += LHAT[i*15+j]*P[i*3+c];
      wcomb_h[n*64 + j*3+c] = (half_t)s;
    }
  for (int k=45;k<64;k++) wcomb_h[n*64+k] = (half_t)0.f;
  float b = bih0[n] + bhh0[n];
  #pragma unroll
  for (int i=0;i<15;i++)
    #pragma unroll
    for (int cp=0;cp<3;cp++) b += wrow[i*3+cp]*cb[cp];
  biasc[n] = b;
}

// ---- K0b: x1 [N,C,T,V,M] fp32 -> xt [t*1024+nm][64] fp16 (features v*3+c, 45 valid)
__global__ void k_xpose(const float* __restrict__ x1, half_t* __restrict__ xt) {
  const int id = blockIdx.x*256 + threadIdx.x;   // exactly 512*3*300*15 = 6,912,000
  const int v  = id % 15;
  const int r1 = id / 15;
  const int t  = r1 % 300;
  const int r2 = r1 / 300;
  const int c  = r2 % 3;
  const int n  = r2 / 3;
  const float2 f = ((const float2*)x1)[id];      // m=0,1 pair, coalesced
  const size_t row = (size_t)t*NMB + n*2;
  xt[row*64     + v*3 + c] = (half_t)f.x;
  xt[(row+1)*64 + v*3 + c] = (half_t)f.y;
}

// ---- Fused 2-layer LSTM + FC + softmax. 256 WGs x 256 threads (4 waves, 1/SIMD,
// 512-reg budget so all 3 weight matrices stay VGPR-resident). 4 batch rows/WG.
// A-fragments use row l16&3 (batch rows replicated 4x across the 16 M-rows) so every
// quad's C-fragment holds all 4 batch rows -> gate math needs no cross-lane moves:
// lane (quad,l16) extracts component `quad` and owns (row=quad, cols hf*64+wave*16+l16).
// Layer-1 runs one step behind layer-0; single barrier per step.
__launch_bounds__(256, 1)
__global__ void k_fused(const half_t* __restrict__ xt, const half_t* __restrict__ wch,
                        const float* __restrict__ biasc, const float* __restrict__ whh0,
                        const float* __restrict__ wih1, const float* __restrict__ whh1,
                        const float* __restrict__ bih1, const float* __restrict__ bhh1,
                        const float* __restrict__ fcw, const float* __restrict__ fcb,
                        float* __restrict__ out) {
  __shared__ __align__(16) half_t h0b[2][4*136];
  __shared__ __align__(16) half_t h1b[2][4*136];
  __shared__ __align__(16) float  gxs[4*BSS*8*16*4];   // 48 KB: wave-private x-proj stash
  __shared__ float logits_lds[240];
  const int tid = threadIdx.x;
  const int wave = tid>>6, lane = tid&63, quad = lane>>4, l16 = lane&15;
  const int nm0 = blockIdx.x*4;
  for (int i=tid; i<2*4*136; i+=256) { (&h0b[0][0])[i] = (half_t)0.f; (&h1b[0][0])[i] = (half_t)0.f; }

  // Resident weight B-frags: B[k][n] = W[gcol][k]; gcol = gate*128 + hf*64 + wave*16 + l16
  half8 whh0F[8][4], wih1F[8][4], whh1F[8][4];
  float bias0[8], bias1[8];
  #pragma unroll
  for (int nt=0; nt<8; nt++) {
    const int gcol = (nt>>1)*128 + (nt&1)*64 + wave*16 + l16;
    #pragma unroll
    for (int kc=0; kc<4; kc++) {
      whh0F[nt][kc] = load_w8(whh0 + gcol*128 + kc*32 + quad*8);
      wih1F[nt][kc] = load_w8(wih1 + gcol*128 + kc*32 + quad*8);
      whh1F[nt][kc] = load_w8(whh1 + gcol*128 + kc*32 + quad*8);
    }
    bias0[nt] = biasc[gcol];
    bias1[nt] = bih1[gcol] + bhh1[gcol];
  }
  float cst0[2] = {0.f,0.f}, cst1[2] = {0.f,0.f};
  float* gxw = gxs + wave*(BSS*8*16*4);
  __syncthreads();

  for (int bs = 0; bs < T_STEPS; bs += BSS) {
    // ---- phase A: x-projection for steps bs..bs+BSS-1 (wave-private, no barrier)
    {
      half8 wchF[8][2];
      #pragma unroll
      for (int nt=0; nt<8; nt++) {
        const int gcol = (nt>>1)*128 + (nt&1)*64 + wave*16 + l16;
        wchF[nt][0] = *(const half8*)(wch + gcol*64 +      quad*8);
        wchF[nt][1] = *(const half8*)(wch + gcol*64 + 32 + quad*8);
      }
      const half_t* xp = xt + ((size_t)bs*NMB + nm0 + (l16&3))*64 + quad*8;
      for (int s = 0; s < BSS; s++) {
        half8 xv0 = *(const half8*)(xp);
        half8 xv1 = *(const half8*)(xp + 32);
        xp += (size_t)NMB*64;
        #pragma unroll
        for (int nt=0; nt<8; nt++) {
          floatx4 a = {0.f,0.f,0.f,0.f};
          a = __builtin_amdgcn_mfma_f32_16x16x32_f16(xv0, wchF[nt][0], a, 0,0,0);
          a = __builtin_amdgcn_mfma_f32_16x16x32_f16(xv1, wchF[nt][1], a, 0,0,0);
          if (quad == 0) *(floatx4*)(gxw + ((s*8+nt)*16 + l16)*4) = a;
        }
      }
    }
    // ---- phase B: recurrent steps
    for (int s = 0; s < BSS; s++) {
      const int t = bs + s;
      const half_t* h0r = &h0b[t&1][0];
      const half_t* h1r = &h1b[t&1][0];
      half8 hA[4], hB[4];
      #pragma unroll
      for (int kc=0; kc<4; kc++) {
        hA[kc] = *(const half8*)(h0r + (l16&3)*136 + kc*32 + quad*8);
        hB[kc] = *(const half8*)(h1r + (l16&3)*136 + kc*32 + quad*8);
      }
      // layer 0: gates = h0[t-1] @ Whh0^T + gx[t]
      floatx4 acc[8];
      #pragma unroll
      for (int nt=0; nt<8; nt++) { floatx4 z = {0.f,0.f,0.f,0.f}; acc[nt] = z; }
      #pragma unroll
      for (int kc=0; kc<4; kc++)
        #pragma unroll
        for (int nt=0; nt<8; nt++)
          acc[nt] = __builtin_amdgcn_mfma_f32_16x16x32_f16(hA[kc], whh0F[nt][kc], acc[nt], 0,0,0);
      float g0[8];
      #pragma unroll
      for (int nt=0; nt<8; nt++)
        g0[nt] = acc[nt][quad] + gxw[(s*8+nt)*64 + l16*4 + quad];
      // layer 1 (computes step t-1): h0[t-1] @ Wih1^T + h1[t-2] @ Whh1^T
      #pragma unroll
      for (int nt=0; nt<8; nt++) { floatx4 z = {0.f,0.f,0.f,0.f}; acc[nt] = z; }
      #pragma unroll
      for (int kc=0; kc<4; kc++)
        #pragma unroll
        for (int nt=0; nt<8; nt++)
          acc[nt] = __builtin_amdgcn_mfma_f32_16x16x32_f16(hA[kc], wih1F[nt][kc], acc[nt], 0,0,0);
      #pragma unroll
      for (int kc=0; kc<4; kc++)
        #pragma unroll
        for (int nt=0; nt<8; nt++)
          acc[nt] = __builtin_amdgcn_mfma_f32_16x16x32_f16(hB[kc], whh1F[nt][kc], acc[nt], 0,0,0);
      // layer-0 nonlinearity + h0 write (lane owns row=quad, cols hf*64+wave*16+l16)
      #pragma unroll
      for (int hf=0; hf<2; hf++) {
        const float gi = g0[hf]   + bias0[hf];
        const float gf = g0[2+hf] + bias0[2+hf];
        const float gg = g0[4+hf] + bias0[4+hf];
        const float go = g0[6+hf] + bias0[6+hf];
        cst0[hf] = fsig(gf)*cst0[hf] + fsig(gi)*ftanh(gg);
        h0b[(t+1)&1][quad*136 + hf*64 + wave*16 + l16] = (half_t)(fsig(go)*ftanh(cst0[hf]));
      }
      float g1[8];
      #pragma unroll
      for (int nt=0; nt<8; nt++) g1[nt] = acc[nt][quad];
      if (t > 0) {
        #pragma unroll
        for (int hf=0; hf<2; hf++) {
          const float gi = g1[hf]   + bias1[hf];
          const float gf = g1[2+hf] + bias1[2+hf];
          const float gg = g1[4+hf] + bias1[4+hf];
          const float go = g1[6+hf] + bias1[6+hf];
          cst1[hf] = fsig(gf)*cst1[hf] + fsig(gi)*ftanh(gg);
          h1b[(t+1)&1][quad*136 + hf*64 + wave*16 + l16] = (half_t)(fsig(go)*ftanh(cst1[hf]));
        }
      }
      __syncthreads();
    }
  }

  // ---- peeled final layer-1 step (t=299): reads h0[299]=h0b[0], h1[298]=h1b[0]
  {
    half8 hA[4], hB[4];
    #pragma unroll
    for (int kc=0; kc<4; kc++) {
      hA[kc] = *(const half8*)(&h0b[0][0] + (l16&3)*136 + kc*32 + quad*8);
      hB[kc] = *(const half8*)(&h1b[0][0] + (l16&3)*136 + kc*32 + quad*8);
    }
    floatx4 acc[8];
    #pragma unroll
    for (int nt=0; nt<8; nt++) { floatx4 z = {0.f,0.f,0.f,0.f}; acc[nt] = z; }
    #pragma unroll
    for (int kc=0; kc<4; kc++)
      #pragma unroll
      for (int nt=0; nt<8; nt++)
        acc[nt] = __builtin_amdgcn_mfma_f32_16x16x32_f16(hA[kc], wih1F[nt][kc], acc[nt], 0,0,0);
    #pragma unroll
    for (int kc=0; kc<4; kc++)
      #pragma unroll
      for (int nt=0; nt<8; nt++)
        acc[nt] = __builtin_amdgcn_mfma_f32_16x16x32_f16(hB[kc], whh1F[nt][kc], acc[nt], 0,0,0);
    #pragma unroll
    for (int hf=0; hf<2; hf++) {
      const float gi = acc[0+hf][quad] + bias1[hf];
      const float gf = acc[2+hf][quad] + bias1[2+hf];
      const float gg = acc[4+hf][quad] + bias1[4+hf];
      const float go = acc[6+hf][quad] + bias1[6+hf];
      cst1[hf] = fsig(gf)*cst1[hf] + fsig(gi)*ftanh(gg);
      h1b[1][quad*136 + hf*64 + wave*16 + l16] = (half_t)(fsig(go)*ftanh(cst1[hf]));
    }
  }
  __syncthreads();

  // ---- FC (60 classes) + softmax; h1[299] in h1b[1] rows 0..3
  if (tid < 240) {
    const int r2 = tid/60, cls = tid%60;
    float s = fcb[cls];
    for (int k2=0; k2<128; k2++) s += (float)h1b[1][r2*136+k2] * fcw[cls*128+k2];
    logits_lds[r2*60+cls] = s;
  }
  __syncthreads();
  if (tid < 4) {
    float m = -1e30f;
    for (int j=0; j<60; j++) m = fmaxf(m, logits_lds[tid*60+j]);
    float s = 0.f;
    for (int j=0; j<60; j++) s += __expf(logits_lds[tid*60+j]-m);
    const float inv = frcp(s);
    for (int j=0; j<60; j++) out[(nm0+tid)*60+j] = __expf(logits_lds[tid*60+j]-m)*inv;
  }
}

extern "C" void kernel_launch(void* const* d_in, const int* in_sizes, int n_in,
                              void* d_out, int out_size, void* d_ws, size_t ws_size,
                              hipStream_t stream) {
  const float* x1      = (const float*)d_in[0];
  const float* cheb_w0 = (const float*)d_in[2];
  const float* cheb_w1 = (const float*)d_in[3];
  const float* cheb_b  = (const float*)d_in[4];
  const float* wih0    = (const float*)d_in[5];
  const float* whh0    = (const float*)d_in[6];
  const float* bih0    = (const float*)d_in[7];
  const float* bhh0    = (const float*)d_in[8];
  const float* wih1    = (const float*)d_in[9];
  const float* whh1    = (const float*)d_in[10];
  const float* bih1    = (const float*)d_in[11];
  const float* bhh1    = (const float*)d_in[12];
  const float* fc_w    = (const float*)d_in[13];
  const float* fc_b    = (const float*)d_in[14];

  char* ws = (char*)d_ws;
  half_t* xt    = (half_t*)(ws + XT_OFF);
  half_t* wch   = (half_t*)(ws + WCH_OFF);
  float*  biasc = (float*)(ws + BC_OFF);

  k_prep <<<dim3(1),     dim3(512), 0, stream>>>(cheb_w0, cheb_w1, cheb_b, wih0, bih0, bhh0, wch, biasc);
  k_xpose<<<dim3(27000), dim3(256), 0, stream>>>(x1, xt);
  k_fused<<<dim3(256),   dim3(256), 0, stream>>>(xt, wch, biasc, whh0, wih1, whh1,
                                                 bih1, bhh1, fc_w, fc_b, (float*)d_out);
}

// Round 6
// 895.272 us; speedup vs baseline: 1.8654x; 1.8654x over previous
//
#include <hip/hip_runtime.h>
#include <hip/hip_fp16.h>

typedef _Float16 half_t;
typedef _Float16 half8 __attribute__((ext_vector_type(8)));
typedef float floatx4 __attribute__((ext_vector_type(4)));
typedef int   int4v  __attribute__((ext_vector_type(4)));

// ---- sizes ----
#define T_STEPS 300
#define NMB     1024                 // N*M batch

// ws layout (bytes)
#define XT_OFF   0ULL
#define XT_BYTES ((unsigned long long)(T_STEPS*NMB + 16)*64*2)
#define HS0_OFF  (XT_OFF + XT_BYTES)
#define HS0_BYTES ((unsigned long long)(T_STEPS*NMB + 16)*128*2)
#define WCH_OFF  (HS0_OFF + HS0_BYTES)        // wcomb as f16 [512][64]
#define WCH_BYTES (512ULL*64*2)
#define BC_OFF   (WCH_OFF + WCH_BYTES)        // biasc f32 [512]

// L_hat = -D^-1/2 A D^-1/2 for the hardcoded 15-node skeleton (row=dst, col=src)
#define S2 0.70710678118654752f
#define QH 0.5f
#define UU 0.40824829046386302f
#define TH 0.33333333333333333f
__constant__ float LHAT[225] = {
  0,0,-S2,0,0,0,0,0,0,0,0,0,0,0,0,
  0,0,0,-S2,0,0,0,0,0,0,0,0,0,0,0,
  -S2,0,0,0,-QH,0,0,0,0,0,0,0,0,0,0,
  0,-S2,0,0,0,-QH,0,0,0,0,0,0,0,0,0,
  0,0,-QH,0,0,0,0,0,0,0,0,0,0,0,-UU,
  0,0,0,-QH,0,0,0,0,0,0,0,0,0,0,-UU,
  0,0,0,0,0,0,0,0,-S2,0,0,0,0,0,0,
  0,0,0,0,0,0,0,0,0,-S2,0,0,0,0,0,
  0,0,0,0,0,0,-S2,0,0,0,-QH,0,0,0,0,
  0,0,0,0,0,0,0,-S2,0,0,0,-QH,0,0,0,
  0,0,0,0,0,0,0,0,-QH,0,0,0,0,-UU,0,
  0,0,0,0,0,0,0,0,0,-QH,0,0,0,-UU,0,
  0,0,0,0,0,0,0,0,0,0,0,0,0,0,0,
  0,0,0,0,0,0,0,0,0,0,-UU,-UU,0,0,0,
  0,0,0,0,-UU,-UU,0,0,0,0,0,0,0,-TH,0
};

// Fast gate math: v_exp_f32 + v_rcp_f32 (approx, ~1 ulp).
__device__ __forceinline__ float frcp(float x)  { return __builtin_amdgcn_rcpf(x); }
__device__ __forceinline__ float fsig(float x)  { return frcp(1.f + __expf(-x)); }
__device__ __forceinline__ float ftanh(float x) { return 2.f*frcp(1.f + __expf(-2.f*x)) - 1.f; }

__device__ __forceinline__ half8 load_w8(const float* p) {
  const float4* q = (const float4*)p;
  float4 a = q[0], b = q[1];
  half8 f;
  f[0]=(half_t)a.x; f[1]=(half_t)a.y; f[2]=(half_t)a.z; f[3]=(half_t)a.w;
  f[4]=(half_t)b.x; f[5]=(half_t)b.y; f[6]=(half_t)b.z; f[7]=(half_t)b.w;
  return f;
}

// Force true register residency: the asm output is opaque, so the compiler
// cannot rematerialize the load+convert chain inside the t-loop (R3's bug:
// VGPR_Count=100 < 128 frag regs, FETCH 2x expected -> weights re-loaded/step).
__device__ __forceinline__ void pin(half8& f) {
  int4v t = __builtin_bit_cast(int4v, f);
  asm volatile("" : "+v"(t));
  f = __builtin_bit_cast(half8, t);
}

// ---- K0: fold ChebConv into layer-0 input projection: wcomb_h f16[512][64], biasc[512]
__global__ void k_prep(const float* __restrict__ w0, const float* __restrict__ w1,
                       const float* __restrict__ cb, const float* __restrict__ wih0,
                       const float* __restrict__ bih0, const float* __restrict__ bhh0,
                       half_t* __restrict__ wcomb_h, float* __restrict__ biasc) {
  const int n = threadIdx.x; // 512 threads, 1 block
  float wrow[45];
  #pragma unroll
  for (int i=0;i<45;i++) wrow[i] = wih0[n*45+i];
  float P[45];
  #pragma unroll
  for (int i=0;i<15;i++)
    #pragma unroll
    for (int c=0;c<3;c++) {
      float s = 0.f;
      #pragma unroll
      for (int cp=0;cp<3;cp++) s += wrow[i*3+cp]*w1[cp*3+c];
      P[i*3+c] = s;
    }
  #pragma unroll
  for (int j=0;j<15;j++)
    #pragma unroll
    for (int c=0;c<3;c++) {
      float s = 0.f;
      #pragma unroll
      for (int cp=0;cp<3;cp++) s += wrow[j*3+cp]*w0[cp*3+c];
      #pragma unroll
      for (int i=0;i<15;i++) s += LHAT[i*15+j]*P[i*3+c];
      wcomb_h[n*64 + j*3+c] = (half_t)s;
    }
  for (int k=45;k<64;k++) wcomb_h[n*64+k] = (half_t)0.f;
  float b = bih0[n] + bhh0[n];
  #pragma unroll
  for (int i=0;i<15;i++)
    #pragma unroll
    for (int cp=0;cp<3;cp++) b += wrow[i*3+cp]*cb[cp];
  biasc[n] = b;
}

// ---- K0b: x1 [N,C,T,V,M] fp32 -> xt [t*1024+nm][64] fp16 (features v*3+c, 45 valid)
__global__ void k_xpose(const float* __restrict__ x1, half_t* __restrict__ xt) {
  const int id = blockIdx.x*256 + threadIdx.x;   // exactly 512*3*300*15 = 6,912,000
  const int v  = id % 15;
  const int r1 = id / 15;
  const int t  = r1 % 300;
  const int r2 = r1 / 300;
  const int c  = r2 % 3;
  const int n  = r2 / 3;
  const float2 f = ((const float2*)x1)[id];      // m=0,1 pair, coalesced
  const size_t row = (size_t)t*NMB + n*2;
  xt[row*64     + v*3 + c] = (half_t)f.x;
  xt[(row+1)*64 + v*3 + c] = (half_t)f.y;
}

// ---- KA: layer-0 LSTM. 256 WGs x 512 threads; 4 batch rows/WG.
// Wave owns cols wave*16+l16 for all 4 gates (nt=gate). A-frags row-replicated
// (row = l16&3) so each lane's C-frag holds all 4 batch rows; lane extracts
// component `quad` -> owns (row=quad, col=wave*16+l16), gate math all-lane,
// cell state = 1 scalar reg. Single barrier/step; h double-buffered in LDS.
__launch_bounds__(512, 2)
__global__ void k_lstm0(const half_t* __restrict__ xt, const half_t* __restrict__ wch,
                        const float* __restrict__ biasc, const float* __restrict__ whh0,
                        half_t* __restrict__ hs0) {
  __shared__ __align__(16) half_t h_lds[2][4*136];
  const int tid = threadIdx.x;
  const int wave = tid>>6, lane = tid&63, quad = lane>>4, l16 = lane&15;
  const int nm0 = blockIdx.x*4;
  for (int i=tid; i<2*4*136; i+=512) (&h_lds[0][0])[i] = (half_t)0.f;

  // Resident weight B-frags: B[k][n] = W[gcol][k]; gcol = nt*128 + wave*16 + l16
  half8 whhF[4][4];
  half8 wcF [4][2];
  float bias[4];
  #pragma unroll
  for (int nt=0; nt<4; nt++) {
    const int gcol = nt*128 + wave*16 + l16;
    #pragma unroll
    for (int kc=0; kc<4; kc++) { whhF[nt][kc] = load_w8(whh0 + gcol*128 + kc*32 + quad*8); pin(whhF[nt][kc]); }
    #pragma unroll
    for (int kc=0; kc<2; kc++) { wcF[nt][kc] = *(const half8*)(wch + gcol*64 + kc*32 + quad*8); pin(wcF[nt][kc]); }
    bias[nt] = biasc[gcol];
  }
  float cst = 0.f;   // lane owns (row=quad, col=wave*16+l16)

  half8 xv[2], xvn[2];
  { const size_t row = (size_t)nm0 + (l16&3);   // t = 0, row-replicated
    xv[0] = *(const half8*)(xt + row*64 +      quad*8);
    xv[1] = *(const half8*)(xt + row*64 + 32 + quad*8);
  }
  __syncthreads();

  for (int t=0; t<T_STEPS; t++) {
    const int tn = (t+1 < T_STEPS) ? t+1 : T_STEPS-1;
    { const size_t row = (size_t)tn*NMB + nm0 + (l16&3);   // prefetch next x
      xvn[0] = *(const half8*)(xt + row*64 +      quad*8);
      xvn[1] = *(const half8*)(xt + row*64 + 32 + quad*8);
    }
    half8 hA[4];
    #pragma unroll
    for (int kc=0; kc<4; kc++)
      hA[kc] = *(const half8*)(&h_lds[t&1][0] + (l16&3)*136 + kc*32 + quad*8);

    floatx4 acc[4];
    #pragma unroll
    for (int nt=0; nt<4; nt++) {
      floatx4 a = {0.f,0.f,0.f,0.f};
      a = __builtin_amdgcn_mfma_f32_16x16x32_f16(xv[0], wcF[nt][0], a, 0,0,0);
      a = __builtin_amdgcn_mfma_f32_16x16x32_f16(xv[1], wcF[nt][1], a, 0,0,0);
      #pragma unroll
      for (int kc=0; kc<4; kc++)
        a = __builtin_amdgcn_mfma_f32_16x16x32_f16(hA[kc], whhF[nt][kc], a, 0,0,0);
      acc[nt] = a;
    }
    {
      const float gi = acc[0][quad] + bias[0];
      const float gf = acc[1][quad] + bias[1];
      const float gg = acc[2][quad] + bias[2];
      const float go = acc[3][quad] + bias[3];
      cst = fsig(gf)*cst + fsig(gi)*ftanh(gg);
      const half_t h = (half_t)(fsig(go)*ftanh(cst));
      h_lds[(t+1)&1][quad*136 + wave*16 + l16] = h;
      hs0[((size_t)t*NMB + nm0 + quad)*128 + wave*16 + l16] = h;
    }
    xv[0] = xvn[0]; xv[1] = xvn[1];
    __syncthreads();
  }
}

// ---- KB: layer-1 LSTM (input from hs0) + FC + softmax
__launch_bounds__(512, 2)
__global__ void k_lstm1(const half_t* __restrict__ hs0, const float* __restrict__ wih1,
                        const float* __restrict__ whh1, const float* __restrict__ bih1,
                        const float* __restrict__ bhh1, const float* __restrict__ fcw,
                        const float* __restrict__ fcb, float* __restrict__ out) {
  __shared__ __align__(16) half_t h_lds[2][4*136];
  __shared__ float logits_lds[240];
  const int tid = threadIdx.x;
  const int wave = tid>>6, lane = tid&63, quad = lane>>4, l16 = lane&15;
  const int nm0 = blockIdx.x*4;
  for (int i=tid; i<2*4*136; i+=512) (&h_lds[0][0])[i] = (half_t)0.f;

  half8 wxF[4][4], whF[4][4];
  float bias[4];
  #pragma unroll
  for (int nt=0; nt<4; nt++) {
    const int gcol = nt*128 + wave*16 + l16;
    #pragma unroll
    for (int kc=0; kc<4; kc++) {
      wxF[nt][kc] = load_w8(wih1 + gcol*128 + kc*32 + quad*8); pin(wxF[nt][kc]);
      whF[nt][kc] = load_w8(whh1 + gcol*128 + kc*32 + quad*8); pin(whF[nt][kc]);
    }
    bias[nt] = bih1[gcol] + bhh1[gcol];
  }
  float cst = 0.f;

  half8 xv[4], xvn[4];
  { const size_t row = (size_t)nm0 + (l16&3);   // t = 0
    #pragma unroll
    for (int kc=0; kc<4; kc++) xv[kc] = *(const half8*)(hs0 + row*128 + kc*32 + quad*8);
  }
  __syncthreads();

  for (int t=0; t<T_STEPS; t++) {
    const int tn = (t+1 < T_STEPS) ? t+1 : T_STEPS-1;
    { const size_t row = (size_t)tn*NMB + nm0 + (l16&3);
      #pragma unroll
      for (int kc=0; kc<4; kc++) xvn[kc] = *(const half8*)(hs0 + row*128 + kc*32 + quad*8);
    }
    half8 hA[4];
    #pragma unroll
    for (int kc=0; kc<4; kc++)
      hA[kc] = *(const half8*)(&h_lds[t&1][0] + (l16&3)*136 + kc*32 + quad*8);

    floatx4 acc[4];
    #pragma unroll
    for (int nt=0; nt<4; nt++) {
      floatx4 a = {0.f,0.f,0.f,0.f};
      #pragma unroll
      for (int kc=0; kc<4; kc++)
        a = __builtin_amdgcn_mfma_f32_16x16x32_f16(xv[kc], wxF[nt][kc], a, 0,0,0);
      #pragma unroll
      for (int kc=0; kc<4; kc++)
        a = __builtin_amdgcn_mfma_f32_16x16x32_f16(hA[kc], whF[nt][kc], a, 0,0,0);
      acc[nt] = a;
    }
    {
      const float gi = acc[0][quad] + bias[0];
      const float gf = acc[1][quad] + bias[1];
      const float gg = acc[2][quad] + bias[2];
      const float go = acc[3][quad] + bias[3];
      cst = fsig(gf)*cst + fsig(gi)*ftanh(gg);
      h_lds[(t+1)&1][quad*136 + wave*16 + l16] = (half_t)(fsig(go)*ftanh(cst));
    }
    #pragma unroll
    for (int kc=0; kc<4; kc++) xv[kc] = xvn[kc];
    __syncthreads();
  }

  // ---- FC (60 classes) + softmax; h_last (t=299) in h_lds[0] rows 0..3
  if (tid < 240) {
    const int r2 = tid/60, cls = tid%60;
    float s = fcb[cls];
    for (int k2=0; k2<128; k2++) s += (float)h_lds[0][r2*136+k2] * fcw[cls*128+k2];
    logits_lds[r2*60+cls] = s;
  }
  __syncthreads();
  if (tid < 4) {
    float m = -1e30f;
    for (int j=0; j<60; j++) m = fmaxf(m, logits_lds[tid*60+j]);
    float s = 0.f;
    for (int j=0; j<60; j++) s += __expf(logits_lds[tid*60+j]-m);
    const float inv = frcp(s);
    for (int j=0; j<60; j++) out[(nm0+tid)*60+j] = __expf(logits_lds[tid*60+j]-m)*inv;
  }
}

extern "C" void kernel_launch(void* const* d_in, const int* in_sizes, int n_in,
                              void* d_out, int out_size, void* d_ws, size_t ws_size,
                              hipStream_t stream) {
  const float* x1      = (const float*)d_in[0];
  const float* cheb_w0 = (const float*)d_in[2];
  const float* cheb_w1 = (const float*)d_in[3];
  const float* cheb_b  = (const float*)d_in[4];
  const float* wih0    = (const float*)d_in[5];
  const float* whh0    = (const float*)d_in[6];
  const float* bih0    = (const float*)d_in[7];
  const float* bhh0    = (const float*)d_in[8];
  const float* wih1    = (const float*)d_in[9];
  const float* whh1    = (const float*)d_in[10];
  const float* bih1    = (const float*)d_in[11];
  const float* bhh1    = (const float*)d_in[12];
  const float* fc_w    = (const float*)d_in[13];
  const float* fc_b    = (const float*)d_in[14];

  char* ws = (char*)d_ws;
  half_t* xt    = (half_t*)(ws + XT_OFF);
  half_t* hs0   = (half_t*)(ws + HS0_OFF);
  half_t* wch   = (half_t*)(ws + WCH_OFF);
  float*  biasc = (float*)(ws + BC_OFF);

  k_prep <<<dim3(1),     dim3(512), 0, stream>>>(cheb_w0, cheb_w1, cheb_b, wih0, bih0, bhh0, wch, biasc);
  k_xpose<<<dim3(27000), dim3(256), 0, stream>>>(x1, xt);
  k_lstm0<<<dim3(256),   dim3(512), 0, stream>>>(xt, wch, biasc, whh0, hs0);
  k_lstm1<<<dim3(256),   dim3(512), 0, stream>>>(hs0, wih1, whh1, bih1, bhh1, fc_w, fc_b, (float*)d_out);
}

// Round 7
// 622.482 us; speedup vs baseline: 2.6829x; 1.4382x over previous
//
#include <hip/hip_runtime.h>
#include <hip/hip_fp16.h>

typedef _Float16 half_t;
typedef _Float16 half8 __attribute__((ext_vector_type(8)));
typedef float floatx4 __attribute__((ext_vector_type(4)));
typedef int   int4v  __attribute__((ext_vector_type(4)));

// ---- sizes ----
#define T_STEPS 300
#define NMB     1024                 // N*M batch
#define BS      16                   // steps per staged block
#define NBLK    19                   // ceil(300/16)

// ws layout (bytes)
#define XT_OFF   0ULL
#define XT_BYTES ((unsigned long long)(T_STEPS*NMB + 16)*64*2)
#define HS0_OFF  (XT_OFF + XT_BYTES)
#define HS0_BYTES ((unsigned long long)(T_STEPS*NMB + 16)*128*2)
#define WCH_OFF  (HS0_OFF + HS0_BYTES)        // wcomb as f16 [512][64]
#define WCH_BYTES (512ULL*64*2)
#define BC_OFF   (WCH_OFF + WCH_BYTES)        // biasc f32 [512]

// L_hat = -D^-1/2 A D^-1/2 for the hardcoded 15-node skeleton (row=dst, col=src)
#define S2 0.70710678118654752f
#define QH 0.5f
#define UU 0.40824829046386302f
#define TH 0.33333333333333333f
__constant__ float LHAT[225] = {
  0,0,-S2,0,0,0,0,0,0,0,0,0,0,0,0,
  0,0,0,-S2,0,0,0,0,0,0,0,0,0,0,0,
  -S2,0,0,0,-QH,0,0,0,0,0,0,0,0,0,0,
  0,-S2,0,0,0,-QH,0,0,0,0,0,0,0,0,0,
  0,0,-QH,0,0,0,0,0,0,0,0,0,0,0,-UU,
  0,0,0,-QH,0,0,0,0,0,0,0,0,0,0,-UU,
  0,0,0,0,0,0,0,0,-S2,0,0,0,0,0,0,
  0,0,0,0,0,0,0,0,0,-S2,0,0,0,0,0,
  0,0,0,0,0,0,-S2,0,0,0,-QH,0,0,0,0,
  0,0,0,0,0,0,0,-S2,0,0,0,-QH,0,0,0,
  0,0,0,0,0,0,0,0,-QH,0,0,0,0,-UU,0,
  0,0,0,0,0,0,0,0,0,-QH,0,0,0,-UU,0,
  0,0,0,0,0,0,0,0,0,0,0,0,0,0,0,
  0,0,0,0,0,0,0,0,0,0,-UU,-UU,0,0,0,
  0,0,0,0,-UU,-UU,0,0,0,0,0,0,0,-TH,0
};

// Fast gate math: v_exp_f32 + v_rcp_f32 (approx, ~1 ulp).
__device__ __forceinline__ float frcp(float x)  { return __builtin_amdgcn_rcpf(x); }
__device__ __forceinline__ float fsig(float x)  { return frcp(1.f + __expf(-x)); }
__device__ __forceinline__ float ftanh(float x) { return 2.f*frcp(1.f + __expf(-2.f*x)) - 1.f; }

__device__ __forceinline__ half8 load_w8(const float* p) {
  const float4* q = (const float4*)p;
  float4 a = q[0], b = q[1];
  half8 f;
  f[0]=(half_t)a.x; f[1]=(half_t)a.y; f[2]=(half_t)a.z; f[3]=(half_t)a.w;
  f[4]=(half_t)b.x; f[5]=(half_t)b.y; f[6]=(half_t)b.z; f[7]=(half_t)b.w;
  return f;
}

// Force true register residency of weight fragments (kills per-step remat).
__device__ __forceinline__ void pin(half8& f) {
  int4v t = __builtin_bit_cast(int4v, f);
  asm volatile("" : "+v"(t));
  f = __builtin_bit_cast(half8, t);
}

// ---- K0: fold ChebConv into layer-0 input projection: wcomb_h f16[512][64], biasc[512]
__global__ void k_prep(const float* __restrict__ w0, const float* __restrict__ w1,
                       const float* __restrict__ cb, const float* __restrict__ wih0,
                       const float* __restrict__ bih0, const float* __restrict__ bhh0,
                       half_t* __restrict__ wcomb_h, float* __restrict__ biasc) {
  const int n = threadIdx.x; // 512 threads, 1 block
  float wrow[45];
  #pragma unroll
  for (int i=0;i<45;i++) wrow[i] = wih0[n*45+i];
  float P[45];
  #pragma unroll
  for (int i=0;i<15;i++)
    #pragma unroll
    for (int c=0;c<3;c++) {
      float s = 0.f;
      #pragma unroll
      for (int cp=0;cp<3;cp++) s += wrow[i*3+cp]*w1[cp*3+c];
      P[i*3+c] = s;
    }
  #pragma unroll
  for (int j=0;j<15;j++)
    #pragma unroll
    for (int c=0;c<3;c++) {
      float s = 0.f;
      #pragma unroll
      for (int cp=0;cp<3;cp++) s += wrow[j*3+cp]*w0[cp*3+c];
      #pragma unroll
      for (int i=0;i<15;i++) s += LHAT[i*15+j]*P[i*3+c];
      wcomb_h[n*64 + j*3+c] = (half_t)s;
    }
  for (int k=45;k<64;k++) wcomb_h[n*64+k] = (half_t)0.f;
  float b = bih0[n] + bhh0[n];
  #pragma unroll
  for (int i=0;i<15;i++)
    #pragma unroll
    for (int cp=0;cp<3;cp++) b += wrow[i*3+cp]*cb[cp];
  biasc[n] = b;
}

// ---- K0b: x1 [N,C,T,V,M] fp32 -> xt [t*1024+nm][64] fp16 (features v*3+c, 45 valid)
__global__ void k_xpose(const float* __restrict__ x1, half_t* __restrict__ xt) {
  const int id = blockIdx.x*256 + threadIdx.x;   // exactly 512*3*300*15 = 6,912,000
  const int v  = id % 15;
  const int r1 = id / 15;
  const int t  = r1 % 300;
  const int r2 = r1 / 300;
  const int c  = r2 % 3;
  const int n  = r2 / 3;
  const float2 f = ((const float2*)x1)[id];      // m=0,1 pair, coalesced
  const size_t row = (size_t)t*NMB + n*2;
  xt[row*64     + v*3 + c] = (half_t)f.x;
  xt[(row+1)*64 + v*3 + c] = (half_t)f.y;
}

// ---- KA: layer-0 LSTM. 256 WGs x 512 threads; 4 batch rows/WG.
// x staged to LDS in 16-step blocks (reg-prefetched one block ahead); h kept in a
// 16-deep LDS ring, bulk-stored to hs0 once per block. Steady-state steps have no
// outstanding vmem, so the per-step __syncthreads costs no vmcnt(0) drain.
__launch_bounds__(512, 2)
__global__ void k_lstm0(const half_t* __restrict__ xt, const half_t* __restrict__ wch,
                        const float* __restrict__ biasc, const float* __restrict__ whh0,
                        half_t* __restrict__ hs0) {
  __shared__ __align__(16) half_t xs[2][BS][4][80];    // x rows padded 64->80 (<=2-way banks)
  __shared__ __align__(16) half_t hr[16][4][144];      // h ring, rows padded 128->144
  const int tid = threadIdx.x;
  const int wave = tid>>6, lane = tid&63, quad = lane>>4, l16 = lane&15;
  const int nm0 = blockIdx.x*4;

  // zero ring slot 15 (read as h[-1] at t=0)
  for (int i=tid; i<4*144; i+=512) (&hr[15][0][0])[i] = (half_t)0.f;

  // Resident weight B-frags: B[k][n] = W[gcol][k]; gcol = nt*128 + wave*16 + l16
  half8 whhF[4][4];
  half8 wcF [4][2];
  float bias[4];
  #pragma unroll
  for (int nt=0; nt<4; nt++) {
    const int gcol = nt*128 + wave*16 + l16;
    #pragma unroll
    for (int kc=0; kc<4; kc++) { whhF[nt][kc] = load_w8(whh0 + gcol*128 + kc*32 + quad*8); pin(whhF[nt][kc]); }
    #pragma unroll
    for (int kc=0; kc<2; kc++) { wcF[nt][kc] = *(const half8*)(wch + gcol*64 + kc*32 + quad*8); pin(wcF[nt][kc]); }
    bias[nt] = biasc[gcol];
  }
  float cst = 0.f;   // lane owns (row=quad, col=wave*16+l16)

  // stage mapping: lane loads 16B = 8 halfs of the block's x
  const int sS = tid>>5;          // step in block 0..15
  const int sR = (tid>>3)&3;      // batch row 0..3
  const int sC = (tid&7)*8;       // col 0..56

  float4 ld = *(const float4*)(xt + ((size_t)sS*NMB + nm0 + sR)*64 + sC);  // block 0
  *(half8*)&xs[0][sS][sR][sC] = __builtin_bit_cast(half8, ld);
  __syncthreads();

  for (int b=0; b<NBLK; b++) {
    const int bs = b*BS, buf = b&1;
    const int cnt = (T_STEPS - bs < BS) ? (T_STEPS - bs) : BS;
    if (b+1 < NBLK) {             // prefetch next block into regs (lands in ~1 step)
      int tt = bs + BS + sS; if (tt > 299) tt = 299;
      ld = *(const float4*)(xt + ((size_t)tt*NMB + nm0 + sR)*64 + sC);
    }
    for (int s=0; s<cnt; s++) {
      const int t = bs + s;
      half8 xA[2], hA[4];
      #pragma unroll
      for (int kc=0; kc<2; kc++)
        xA[kc] = *(const half8*)&xs[buf][s][l16&3][kc*32 + quad*8];
      const half_t* hrow = &hr[(t+15)&15][l16&3][0];
      #pragma unroll
      for (int kc=0; kc<4; kc++)
        hA[kc] = *(const half8*)(hrow + kc*32 + quad*8);

      floatx4 acc[4];
      #pragma unroll
      for (int nt=0; nt<4; nt++) {
        floatx4 a = {0.f,0.f,0.f,0.f};
        a = __builtin_amdgcn_mfma_f32_16x16x32_f16(xA[0], wcF[nt][0], a, 0,0,0);
        a = __builtin_amdgcn_mfma_f32_16x16x32_f16(xA[1], wcF[nt][1], a, 0,0,0);
        #pragma unroll
        for (int kc=0; kc<4; kc++)
          a = __builtin_amdgcn_mfma_f32_16x16x32_f16(hA[kc], whhF[nt][kc], a, 0,0,0);
        acc[nt] = a;
      }
      {
        const float gi = acc[0][quad] + bias[0];
        const float gf = acc[1][quad] + bias[1];
        const float gg = acc[2][quad] + bias[2];
        const float go = acc[3][quad] + bias[3];
        cst = fsig(gf)*cst + fsig(gi)*ftanh(gg);
        hr[t&15][quad][wave*16 + l16] = (half_t)(fsig(go)*ftanh(cst));
      }
      __syncthreads();
    }
    // bulk store this block's h to hs0 (one dwordx4 x2 per lane)
    {
      const int hS = tid>>5, hR = (tid>>3)&3, hC = (tid&7)*16;
      if (hS < cnt) {
        half8 a0 = *(const half8*)&hr[(bs+hS)&15][hR][hC];
        half8 a1 = *(const half8*)&hr[(bs+hS)&15][hR][hC+8];
        half_t* dst = hs0 + ((size_t)(bs+hS)*NMB + nm0 + hR)*128 + hC;
        *(half8*)dst = a0; *(half8*)(dst+8) = a1;
      }
    }
    if (b+1 < NBLK)
      *(half8*)&xs[buf^1][sS][sR][sC] = __builtin_bit_cast(half8, ld);
    __syncthreads();
  }
}

// ---- KB: layer-1 LSTM (input from hs0, block-staged) + FC + softmax
__launch_bounds__(512, 2)
__global__ void k_lstm1(const half_t* __restrict__ hs0, const float* __restrict__ wih1,
                        const float* __restrict__ whh1, const float* __restrict__ bih1,
                        const float* __restrict__ bhh1, const float* __restrict__ fcw,
                        const float* __restrict__ fcb, float* __restrict__ out) {
  __shared__ __align__(16) half_t xs[2][BS][4][144];   // hs0 rows padded 128->144
  __shared__ __align__(16) half_t h2[2][4][144];
  __shared__ float logits_lds[240];
  const int tid = threadIdx.x;
  const int wave = tid>>6, lane = tid&63, quad = lane>>4, l16 = lane&15;
  const int nm0 = blockIdx.x*4;
  for (int i=tid; i<4*144; i+=512) (&h2[0][0][0])[i] = (half_t)0.f;

  half8 wxF[4][4], whF[4][4];
  float bias[4];
  #pragma unroll
  for (int nt=0; nt<4; nt++) {
    const int gcol = nt*128 + wave*16 + l16;
    #pragma unroll
    for (int kc=0; kc<4; kc++) {
      wxF[nt][kc] = load_w8(wih1 + gcol*128 + kc*32 + quad*8); pin(wxF[nt][kc]);
      whF[nt][kc] = load_w8(whh1 + gcol*128 + kc*32 + quad*8); pin(whF[nt][kc]);
    }
    bias[nt] = bih1[gcol] + bhh1[gcol];
  }
  float cst = 0.f;

  // stage mapping: lane loads 32B = 16 halfs per block
  const int sS = tid>>5;          // step 0..15
  const int sR = (tid>>3)&3;      // row 0..3
  const int sC = (tid&7)*16;      // col 0..112

  float4 ld0, ld1;
  { const half_t* src = hs0 + ((size_t)sS*NMB + nm0 + sR)*128 + sC;
    ld0 = *(const float4*)src; ld1 = *(const float4*)(src+8); }
  *(half8*)&xs[0][sS][sR][sC]   = __builtin_bit_cast(half8, ld0);
  *(half8*)&xs[0][sS][sR][sC+8] = __builtin_bit_cast(half8, ld1);
  __syncthreads();

  for (int b=0; b<NBLK; b++) {
    const int bs = b*BS, buf = b&1;
    const int cnt = (T_STEPS - bs < BS) ? (T_STEPS - bs) : BS;
    if (b+1 < NBLK) {
      int tt = bs + BS + sS; if (tt > 299) tt = 299;
      const half_t* src = hs0 + ((size_t)tt*NMB + nm0 + sR)*128 + sC;
      ld0 = *(const float4*)src; ld1 = *(const float4*)(src+8);
    }
    for (int s=0; s<cnt; s++) {
      const int t = bs + s;
      half8 xA[4], hA[4];
      const half_t* xrow = &xs[buf][s][l16&3][0];
      const half_t* hrow = &h2[t&1][l16&3][0];
      #pragma unroll
      for (int kc=0; kc<4; kc++) {
        xA[kc] = *(const half8*)(xrow + kc*32 + quad*8);
        hA[kc] = *(const half8*)(hrow + kc*32 + quad*8);
      }
      floatx4 acc[4];
      #pragma unroll
      for (int nt=0; nt<4; nt++) {
        floatx4 a = {0.f,0.f,0.f,0.f};
        #pragma unroll
        for (int kc=0; kc<4; kc++)
          a = __builtin_amdgcn_mfma_f32_16x16x32_f16(xA[kc], wxF[nt][kc], a, 0,0,0);
        #pragma unroll
        for (int kc=0; kc<4; kc++)
          a = __builtin_amdgcn_mfma_f32_16x16x32_f16(hA[kc], whF[nt][kc], a, 0,0,0);
        acc[nt] = a;
      }
      {
        const float gi = acc[0][quad] + bias[0];
        const float gf = acc[1][quad] + bias[1];
        const float gg = acc[2][quad] + bias[2];
        const float go = acc[3][quad] + bias[3];
        cst = fsig(gf)*cst + fsig(gi)*ftanh(gg);
        h2[(t+1)&1][quad][wave*16 + l16] = (half_t)(fsig(go)*ftanh(cst));
      }
      __syncthreads();
    }
    if (b+1 < NBLK) {
      *(half8*)&xs[buf^1][sS][sR][sC]   = __builtin_bit_cast(half8, ld0);
      *(half8*)&xs[buf^1][sS][sR][sC+8] = __builtin_bit_cast(half8, ld1);
    }
    __syncthreads();
  }

  // ---- FC (60 classes) + softmax; h1[299] in h2[0] rows 0..3
  if (tid < 240) {
    const int r2 = tid/60, cls = tid%60;
    float s = fcb[cls];
    for (int k2=0; k2<128; k2++) s += (float)h2[0][r2][k2] * fcw[cls*128+k2];
    logits_lds[r2*60+cls] = s;
  }
  __syncthreads();
  if (tid < 4) {
    float m = -1e30f;
    for (int j=0; j<60; j++) m = fmaxf(m, logits_lds[tid*60+j]);
    float s = 0.f;
    for (int j=0; j<60; j++) s += __expf(logits_lds[tid*60+j]-m);
    const float inv = frcp(s);
    for (int j=0; j<60; j++) out[(nm0+tid)*60+j] = __expf(logits_lds[tid*60+j]-m)*inv;
  }
}

extern "C" void kernel_launch(void* const* d_in, const int* in_sizes, int n_in,
                              void* d_out, int out_size, void* d_ws, size_t ws_size,
                              hipStream_t stream) {
  const float* x1      = (const float*)d_in[0];
  const float* cheb_w0 = (const float*)d_in[2];
  const float* cheb_w1 = (const float*)d_in[3];
  const float* cheb_b  = (const float*)d_in[4];
  const float* wih0    = (const float*)d_in[5];
  const float* whh0    = (const float*)d_in[6];
  const float* bih0    = (const float*)d_in[7];
  const float* bhh0    = (const float*)d_in[8];
  const float* wih1    = (const float*)d_in[9];
  const float* whh1    = (const float*)d_in[10];
  const float* bih1    = (const float*)d_in[11];
  const float* bhh1    = (const float*)d_in[12];
  const float* fc_w    = (const float*)d_in[13];
  const float* fc_b    = (const float*)d_in[14];

  char* ws = (char*)d_ws;
  half_t* xt    = (half_t*)(ws + XT_OFF);
  half_t* hs0   = (half_t*)(ws + HS0_OFF);
  half_t* wch   = (half_t*)(ws + WCH_OFF);
  float*  biasc = (float*)(ws + BC_OFF);

  k_prep <<<dim3(1),     dim3(512), 0, stream>>>(cheb_w0, cheb_w1, cheb_b, wih0, bih0, bhh0, wch, biasc);
  k_xpose<<<dim3(27000), dim3(256), 0, stream>>>(x1, xt);
  k_lstm0<<<dim3(256),   dim3(512), 0, stream>>>(xt, wch, biasc, whh0, hs0);
  k_lstm1<<<dim3(256),   dim3(512), 0, stream>>>(hs0, wih1, whh1, bih1, bhh1, fc_w, fc_b, (float*)d_out);
}